// Round 1
// baseline (216.654 us; speedup 1.0000x reference)
//
#include <hip/hip_runtime.h>
#include <math.h>

// HermiteFuncs: x[B=32, n=64, N=4096] fp32 -> psi[B, n, R=6, N] fp32
// s = tanh(x) * sqrt(13); g = exp(-s^2/2); c = pi^(-1/4)
// psi0 = c*g; psi1 = sqrt(2)*c*s*g;
// psi_k = sqrt(2/k)*s*psi_{k-1} - sqrt((k-1)/k)*psi_{k-2}, k=2..5
//
// Memory-bound (read 33.6MB, write 201MB). One thread per float4 of N;
// 6 coalesced float4 stores per thread (stride 4096 floats = k-slices).

__global__ __launch_bounds__(256) void hermite_kernel(
    const float4* __restrict__ x, float* __restrict__ out, int total4)
{
    int t = blockIdx.x * blockDim.x + threadIdx.x;
    if (t >= total4) return;

    // N/4 = 1024 float4 per (b,n) row
    int row = t >> 10;          // b*64 + n
    int col = t & 1023;         // float4 index within N

    float4 xv = x[t];

    const float SQRT13 = 3.6055512754639896f;   // sqrt(2*6+1)
    const float C0     = 0.7511255444649425f;   // pi^(-1/4)
    const float SQRT2  = 1.4142135623730951f;

    // recurrence constants
    const float a2 = 1.0f,              b2 = 0.7071067811865476f;
    const float a3 = 0.816496580927726f, b3 = 0.816496580927726f;
    const float a4 = 0.7071067811865476f, b4 = 0.8660254037844386f;
    const float a5 = 0.6324555320336759f, b5 = 0.8944271909999159f;

    float4 p[6];
    float* pf = (float*)p;
    const float xs[4] = {xv.x, xv.y, xv.z, xv.w};

#pragma unroll
    for (int j = 0; j < 4; ++j) {
        float s = tanhf(xs[j]) * SQRT13;
        float g = __expf(-0.5f * s * s);
        float p0 = C0 * g;
        float p1 = SQRT2 * C0 * s * g;
        float p2 = a2 * s * p1 - b2 * p0;
        float p3 = a3 * s * p2 - b3 * p1;
        float p4 = a4 * s * p3 - b4 * p2;
        float p5 = a5 * s * p4 - b5 * p3;
        pf[0*4 + j] = p0;
        pf[1*4 + j] = p1;
        pf[2*4 + j] = p2;
        pf[3*4 + j] = p3;
        pf[4*4 + j] = p4;
        pf[5*4 + j] = p5;
    }

    // out[row][k][N] -> base of this row's 6*4096 block, then k-slices
    float4* ob = (float4*)(out + (size_t)row * 6 * 4096) + col;
#pragma unroll
    for (int k = 0; k < 6; ++k) ob[k * 1024] = p[k];
}

extern "C" void kernel_launch(void* const* d_in, const int* in_sizes, int n_in,
                              void* d_out, int out_size, void* d_ws, size_t ws_size,
                              hipStream_t stream) {
    const float4* x = (const float4*)d_in[0];
    float* out = (float*)d_out;
    int total4 = in_sizes[0] / 4;           // 8388608/4 = 2097152
    int block = 256;
    int grid = (total4 + block - 1) / block; // 8192
    hermite_kernel<<<grid, block, 0, stream>>>(x, out, total4);
}

// Round 2
// 216.019 us; speedup vs baseline: 1.0029x; 1.0029x over previous
//
#include <hip/hip_runtime.h>
#include <math.h>

// HermiteFuncs: x[B=32, n=64, N=4096] fp32 -> psi[B, n, R=6, N] fp32
// s = tanh(x)*sqrt(13); g = exp(-s^2/2); c = pi^(-1/4)
// psi0 = c*g; psi1 = sqrt(2)*c*s*g; psi_k = sqrt(2/k)*s*psi_{k-1} - sqrt((k-1)/k)*psi_{k-2}
//
// Memory-bound: read 33.6 MB, write 201 MB -> ~36 us @ 6.6 TB/s.
// R2 changes: (1) nontemporal (nt) stores -- output is streaming, no reuse,
// avoid L2 write-allocate thrash; (2) fast tanh = 1 - 2/(e^{2x}+1)
// (v_exp_f32 + v_rcp_f32) instead of OCML tanhf.

typedef float vf4 __attribute__((ext_vector_type(4)));

__global__ __launch_bounds__(256) void hermite_kernel(
    const vf4* __restrict__ x, float* __restrict__ out, int total4)
{
    int t = blockIdx.x * blockDim.x + threadIdx.x;
    if (t >= total4) return;

    int row = t >> 10;          // b*64 + n   (N/4 = 1024 float4 per row)
    int col = t & 1023;

    vf4 xv = __builtin_nontemporal_load(x + t);

    const float SQRT13 = 3.6055512754639896f;   // sqrt(2*6+1)
    const float C0     = 0.7511255444649425f;   // pi^(-1/4)
    const float SQRT2C = 1.0622519320271968f;   // sqrt(2)*c

    const float a2 = 1.0f,               b2 = 0.7071067811865476f;
    const float a3 = 0.816496580927726f, b3 = 0.816496580927726f;
    const float a4 = 0.7071067811865476f, b4 = 0.8660254037844386f;
    const float a5 = 0.6324555320336759f, b5 = 0.8944271909999159f;

    vf4 p0, p1, p2, p3, p4, p5;
    float* f0 = (float*)&p0; float* f1 = (float*)&p1; float* f2 = (float*)&p2;
    float* f3 = (float*)&p3; float* f4 = (float*)&p4; float* f5 = (float*)&p5;

#pragma unroll
    for (int j = 0; j < 4; ++j) {
        float xval = xv[j];
        // fast tanh: 1 - 2/(e^{2x}+1); saturates correctly for |x| large
        float e2x = __expf(2.0f * xval);
        float r   = __builtin_amdgcn_rcpf(e2x + 1.0f);
        float th  = fmaf(-2.0f, r, 1.0f);
        float s   = th * SQRT13;
        float g   = __expf(-0.5f * s * s);
        float q0 = C0 * g;
        float q1 = SQRT2C * s * g;
        float q2 = a2 * s * q1 - b2 * q0;
        float q3 = a3 * s * q2 - b3 * q1;
        float q4 = a4 * s * q3 - b4 * q2;
        float q5 = a5 * s * q4 - b5 * q3;
        f0[j] = q0; f1[j] = q1; f2[j] = q2; f3[j] = q3; f4[j] = q4; f5[j] = q5;
    }

    vf4* ob = (vf4*)(out + (size_t)row * 6 * 4096) + col;
    __builtin_nontemporal_store(p0, ob);
    __builtin_nontemporal_store(p1, ob + 1024);
    __builtin_nontemporal_store(p2, ob + 2048);
    __builtin_nontemporal_store(p3, ob + 3072);
    __builtin_nontemporal_store(p4, ob + 4096);
    __builtin_nontemporal_store(p5, ob + 5120);
}

extern "C" void kernel_launch(void* const* d_in, const int* in_sizes, int n_in,
                              void* d_out, int out_size, void* d_ws, size_t ws_size,
                              hipStream_t stream) {
    const vf4* x = (const vf4*)d_in[0];
    float* out = (float*)d_out;
    int total4 = in_sizes[0] / 4;            // 2097152
    int block = 256;
    int grid = (total4 + block - 1) / block; // 8192
    hermite_kernel<<<grid, block, 0, stream>>>(x, out, total4);
}